// Round 12
// baseline (512.360 us; speedup 1.0000x reference)
//
#include <hip/hip_runtime.h>
#include <hip/hip_cooperative_groups.h>
#include <hip/hip_bf16.h>

#define NN 200000
#define NE 600000
#define NG 1024
#define HH 512

typedef short short8 __attribute__((ext_vector_type(8)));
typedef float f32x4 __attribute__((ext_vector_type(4)));

__device__ __forceinline__ unsigned short f2bf(float f){
  unsigned u = __float_as_uint(f);
  u += 0x7fffu + ((u >> 16) & 1u);
  return (unsigned short)(u >> 16);
}
__device__ __forceinline__ float bf2f(unsigned short h){
  return __uint_as_float(((unsigned)h) << 16);
}

// packed f32x8 -> bf16x8 (RTNE) via v_cvt_pk_bf16_f32 when available
__device__ __forceinline__ short8 cvt8pk(float4 a, float4 b){
  union { short8 s; __hip_bfloat162 h[4]; } u;
  u.h[0] = __float22bfloat162_rn(make_float2(a.x, a.y));
  u.h[1] = __float22bfloat162_rn(make_float2(a.z, a.w));
  u.h[2] = __float22bfloat162_rn(make_float2(b.x, b.y));
  u.h[3] = __float22bfloat162_rn(make_float2(b.z, b.w));
  return u.s;
}

// f32x8 -> bf16 hi + bf16 lo (split-precision)
__device__ __forceinline__ void split8(const float* v, short8* hi, short8* lo){
  union { short8 s; __hip_bfloat162 h[4]; unsigned u[4]; } H, L;
#pragma unroll
  for (int p=0;p<4;++p){
    float a = v[2*p], b = v[2*p+1];
    H.h[p] = __float22bfloat162_rn(make_float2(a, b));
    unsigned hu = H.u[p];
    L.h[p] = __float22bfloat162_rn(make_float2(a - __uint_as_float(hu << 16),
                                               b - __uint_as_float(hu & 0xffff0000u)));
  }
  *hi = H.s; *lo = L.s;
}

// gelu(x) = x * sigmoid(1.5957691216*x + 0.07135481627*x^3)  (tanh-form GELU)
__device__ __forceinline__ float gelu_f(float x){
  float p = __builtin_fmaf(x*x, -0.10294325f, -2.3022085f);
  float e = __builtin_amdgcn_exp2f(x * p);
  return x * __builtin_amdgcn_rcpf(1.0f + e);
}

// ========== kpre: w1 prep(196) + nstart(782) + edge histogram -> per-block partials(256) ==========
__global__ __launch_bounds__(256) void kpre(
    const float* __restrict__ nfw1, const float* __restrict__ nfb1,
    const float* __restrict__ nfg1, const float* __restrict__ nfbe1,
    const float* __restrict__ efw1, const float* __restrict__ efb1,
    const float* __restrict__ efg1, const float* __restrict__ efbe1,
    unsigned short* __restrict__ w1nT, unsigned short* __restrict__ w1eT,
    float* __restrict__ b1n, float* __restrict__ b1e,
    const int* __restrict__ bidx, int* __restrict__ nstart,
    const int* __restrict__ eidx, int* __restrict__ eg, int* __restrict__ hpart){
  __shared__ int h[NG];
  const float rs = 0.99999500003750f;   // 1/sqrt(1+1e-5)
  int b = blockIdx.x, t = threadIdx.x;
  if (b < 196){
    int tid = b*256 + t;
    if (tid < 512*64){
      int c = tid >> 6, k = tid & 63;
      float w = (k < 41) ? nfw1[k*HH + c] * nfg1[c] * rs : 0.0f;
      w1nT[tid] = f2bf(w);
    } else if (tid < 512*96){
      int u = tid - 512*64; int c = u >> 5, k = u & 31;
      float w = (k < 16) ? efw1[k*HH + c] * efg1[c] * rs : 0.0f;
      w1eT[u] = f2bf(w);
    } else if (tid < 512*96 + 512){
      int c = tid - 512*96;
      b1n[c] = nfb1[c]*nfg1[c]*rs + nfbe1[c];
    } else if (tid < 512*96 + 1024){
      int c = tid - (512*96 + 512);
      b1e[c] = efb1[c]*efg1[c]*rs + efbe1[c];
    }
  } else if (b < 978){
    int i = (b-196)*256 + t;
    if (i < NN){
      int g0 = bidx[i];
      int g1 = (i+1 < NN) ? bidx[i+1] : NG;
      for (int g = g0+1; g <= g1; ++g) nstart[g] = i+1;
      if (i == 0) for (int g = 0; g <= g0; ++g) nstart[g] = 0;
    }
  } else {
    int hb = b - 978;                     // 0..255
    for (int u = t; u < NG; u += 256) h[u] = 0;
    __syncthreads();
    for (int e = hb*256 + t; e < NE; e += 256*256){
      int g = bidx[eidx[e]];
      eg[e] = g;
      atomicAdd(&h[g], 1);
    }
    __syncthreads();
    for (int u = t; u < NG; u += 256) hpart[hb*NG + u] = h[u];
  }
}

// ========== kscan: reduce 256 partial hists + exclusive scan (one block, 1024 threads) ==========
__global__ __launch_bounds__(1024) void kscan(const int* __restrict__ hpart,
    int* __restrict__ cursor, int* __restrict__ estart){
  __shared__ int s[NG];
  int t = threadIdx.x;
  int v = 0;
  for (int hb = 0; hb < 256; ++hb) v += hpart[hb*NG + t];
  s[t] = v; __syncthreads();
  for (int d = 1; d < NG; d <<= 1){
    int x = (t >= d) ? s[t-d] : 0;
    __syncthreads();
    s[t] += x;
    __syncthreads();
  }
  cursor[t] = s[t] - v;
  estart[t] = s[t] - v;
  if (t == NG-1) estart[NG] = s[t];   // == NE
}

// ========== kscatter: counting-sort scatter + gh-init (after estart exists) ==========
__global__ __launch_bounds__(1024) void kscatter(const int* __restrict__ eg, int* __restrict__ cursor,
    int* __restrict__ perm, const int* __restrict__ estart, const int* __restrict__ nstart,
    const float* __restrict__ gf, const float* __restrict__ b2n, const float* __restrict__ b2e,
    float* __restrict__ gh){
  __shared__ int h[NG], base[NG];
  const int per = (NE + gridDim.x - 1) / gridDim.x;
  const int lo = blockIdx.x * per, hi = min(lo + per, NE);
  for (int t = threadIdx.x; t < NG; t += 1024) h[t] = 0;
  __syncthreads();
  for (int e = lo + threadIdx.x; e < hi; e += 1024) atomicAdd(&h[eg[e]], 1);
  __syncthreads();
  for (int t = threadIdx.x; t < NG; t += 1024){
    int c = h[t];
    base[t] = c ? atomicAdd(&cursor[t], c) : 0;
    h[t] = 0;
  }
  __syncthreads();
  for (int e = lo + threadIdx.x; e < hi; e += 1024){
    int g = eg[e];
    int p = base[g] + atomicAdd(&h[g], 1);
    perm[p] = e;
  }
  // gh-init: gh = gf + cntn*b2n + cnte*b2e   (exactly one float4 per thread)
  {
    int i = blockIdx.x*1024 + threadIdx.x;   // 131072 = NG*HH/4
    int f = i*4;
    int r = f >> 9, c = f & 511;
    float cn = (float)(nstart[r+1] - nstart[r]);
    float ce = (float)(estart[r+1] - estart[r]);
    float4 gv = *(const float4*)&gf[f];
    float4 bn4 = *(const float4*)&b2n[c];
    float4 be4 = *(const float4*)&b2e[c];
    float4 o;
    o.x = gv.x + cn*bn4.x + ce*be4.x;
    o.y = gv.y + cn*bn4.y + ce*be4.y;
    o.z = gv.z + cn*bn4.z + ce*be4.z;
    o.w = gv.w + cn*bn4.w + ce*be4.w;
    *(float4*)&gh[f] = o;
  }
}

// ========== fused first layers (round-6 kmain + pk-convert staging) ==========
__global__ __launch_bounds__(256) void kmain(
    const float* __restrict__ nf, const float* __restrict__ dp, const int* __restrict__ ny,
    const int* __restrict__ nstart, const float* __restrict__ ef, const int* __restrict__ perm,
    const int* __restrict__ estart, const unsigned short* __restrict__ w1nT,
    const unsigned short* __restrict__ w1eT, const float* __restrict__ b1n,
    const float* __restrict__ b1e, float* __restrict__ S){
  const int t = threadIdx.x;
  const int lane = t & 63, w = t >> 6;
  const int q = lane >> 4, m = lane & 15;
  const short8 zz = {0,0,0,0,0,0,0,0};
  if (blockIdx.x < 2048){
    // ---------------- EDGE ----------------
    const int g = blockIdx.x >> 1;
    const int c0 = ((blockIdx.x & 1) << 8) + (w << 6);
    short8 bfr[4]; float bias[4]; float colacc[4] = {0.f,0.f,0.f,0.f};
#pragma unroll
    for (int nt=0; nt<4; ++nt){
      int c = c0 + (nt<<4) + m;
      bfr[nt] = *(const short8*)(w1eT + (c << 5) + (q << 3));
      bias[nt] = b1e[c];
    }
    const int s0 = estart[g], s1 = estart[g+1];
    const int nfull = (s1 - s0) >> 4;
    int rb = s0;
    for (int ch=0; ch<nfull; ++ch, rb += 16){
      int e = perm[rb + m];
      short8 f = zz;
      if (q < 2){
        const float4* ap = (const float4*)(ef + (size_t)e*16 + (q<<3));
        f = cvt8pk(ap[0], ap[1]);
      }
#pragma unroll
      for (int nt=0; nt<4; ++nt){
        f32x4 acc = {bias[nt], bias[nt], bias[nt], bias[nt]};
        acc = __builtin_amdgcn_mfma_f32_16x16x32_bf16(f, bfr[nt], acc, 0, 0, 0);
        colacc[nt] += (gelu_f(acc[0]) + gelu_f(acc[1])) + (gelu_f(acc[2]) + gelu_f(acc[3]));
      }
    }
    if (rb < s1){
      int row = rb + m;
      int e = perm[(row < s1) ? row : s0];
      short8 f = zz;
      if (q < 2){
        const float4* ap = (const float4*)(ef + (size_t)e*16 + (q<<3));
        f = cvt8pk(ap[0], ap[1]);
      }
      const int vr = s1 - rb;   // 1..15 valid rows in this chunk
#pragma unroll
      for (int nt=0; nt<4; ++nt){
        f32x4 acc = {bias[nt], bias[nt], bias[nt], bias[nt]};
        acc = __builtin_amdgcn_mfma_f32_16x16x32_bf16(f, bfr[nt], acc, 0, 0, 0);
        float v0 = (q*4+0 < vr) ? gelu_f(acc[0]) : 0.f;
        float v1 = (q*4+1 < vr) ? gelu_f(acc[1]) : 0.f;
        float v2 = (q*4+2 < vr) ? gelu_f(acc[2]) : 0.f;
        float v3 = (q*4+3 < vr) ? gelu_f(acc[3]) : 0.f;
        colacc[nt] += (v0+v1)+(v2+v3);
      }
    }
#pragma unroll
    for (int nt=0; nt<4; ++nt){
      float s = colacc[nt];
      s += __shfl_xor(s, 16); s += __shfl_xor(s, 32);
      if (lane < 16) S[(size_t)g*1024 + 512 + c0 + (nt<<4) + lane] = s;
    }
  } else {
    // ---------------- NODE ----------------
    const int b2 = blockIdx.x - 2048;
    const int g = b2 >> 2;
    const int c0 = ((b2 & 3) << 7) + (w << 5);
    short8 bf0[2], bf1[2]; float bias[2]; float colacc[2] = {0.f,0.f};
#pragma unroll
    for (int nt=0; nt<2; ++nt){
      int c = c0 + (nt<<4) + m;
      const short8* bp = (const short8*)(w1nT + (c << 6) + (q << 3));
      bf0[nt] = bp[0]; bf1[nt] = bp[4];
      bias[nt] = b1n[c];
    }
    const int s0 = nstart[g], s1 = nstart[g+1];
    const int nfull = (s1 - s0) >> 4;
    int rb = s0;
    for (int ch=0; ch<nfull; ++ch, rb += 16){
      int ar = rb + m;
      const float4* ap = (const float4*)(nf + (size_t)ar*32 + (q<<3));
      short8 f = cvt8pk(ap[0], ap[1]);
      int cls = ny[ar];
      short dpb = (short)f2bf(dp[ar]);
      short8 h = zz;
      if (q == 0){
#pragma unroll
        for (int j=0;j<8;++j) h[j] = (cls==j) ? dpb : (short)0;
      } else if (q == 1 && cls == 8) h[0] = dpb;
#pragma unroll
      for (int nt=0; nt<2; ++nt){
        f32x4 acc = {bias[nt], bias[nt], bias[nt], bias[nt]};
        acc = __builtin_amdgcn_mfma_f32_16x16x32_bf16(f, bf0[nt], acc, 0, 0, 0);
        acc = __builtin_amdgcn_mfma_f32_16x16x32_bf16(h, bf1[nt], acc, 0, 0, 0);
        colacc[nt] += (gelu_f(acc[0]) + gelu_f(acc[1])) + (gelu_f(acc[2]) + gelu_f(acc[3]));
      }
    }
    if (rb < s1){
      int row = rb + m;
      int ar = (row < s1) ? row : s0;
      const float4* ap = (const float4*)(nf + (size_t)ar*32 + (q<<3));
      short8 f = cvt8pk(ap[0], ap[1]);
      int cls = ny[ar];
      short dpb = (short)f2bf(dp[ar]);
      short8 h = zz;
      if (q == 0){
#pragma unroll
        for (int j=0;j<8;++j) h[j] = (cls==j) ? dpb : (short)0;
      } else if (q == 1 && cls == 8) h[0] = dpb;
      const int vr = s1 - rb;
#pragma unroll
      for (int nt=0; nt<2; ++nt){
        f32x4 acc = {bias[nt], bias[nt], bias[nt], bias[nt]};
        acc = __builtin_amdgcn_mfma_f32_16x16x32_bf16(f, bf0[nt], acc, 0, 0, 0);
        acc = __builtin_amdgcn_mfma_f32_16x16x32_bf16(h, bf1[nt], acc, 0, 0, 0);
        float v0 = (q*4+0 < vr) ? gelu_f(acc[0]) : 0.f;
        float v1 = (q*4+1 < vr) ? gelu_f(acc[1]) : 0.f;
        float v2 = (q*4+2 < vr) ? gelu_f(acc[2]) : 0.f;
        float v3 = (q*4+3 < vr) ? gelu_f(acc[3]) : 0.f;
        colacc[nt] += (v0+v1)+(v2+v3);
      }
    }
#pragma unroll
    for (int nt=0; nt<2; ++nt){
      float s = colacc[nt];
      s += __shfl_xor(s, 16); s += __shfl_xor(s, 32);
      if (lane < 16) S[(size_t)g*1024 + c0 + (nt<<4) + lane] = s;
    }
  }
}

// ========== LDS-free bf16 split GEMM tile, B direct from fp32 weights (device fn) ==========
__device__ __forceinline__ void gemm_nolds(int cx, int ry,
    const float* __restrict__ A, int lda, int nkc,
    const float* __restrict__ B0, const float* __restrict__ B1,
    float* __restrict__ out, const float* __restrict__ pre, const float* __restrict__ bias,
    const float* __restrict__ gam, const float* __restrict__ bet){
  const int t = threadIdx.x, lane = t & 63, w = t >> 6;
  const int q = lane >> 4, m = lane & 15;
  const int c0 = cx*32, r0 = ry*64 + w*16;
  f32x4 acc[2] = {{0.f,0.f,0.f,0.f},{0.f,0.f,0.f,0.f}};
  const float* ap = A + (size_t)(r0 + m)*lda + (q<<3);
  for (int kc = 0; kc < nkc; ++kc){
    const int ko = kc*32;
    float4 x = *(const float4*)(ap + ko);
    float4 y = *(const float4*)(ap + ko + 4);
    float v[8] = {x.x,x.y,x.z,x.w,y.x,y.y,y.z,y.w};
    short8 ah, al;
    split8(v, &ah, &al);
    const float* Bp = (kc < 16) ? B0 : B1;
    const float* bp = Bp + (size_t)((kc & 15)*32 + (q<<3))*HH + c0 + m;
#pragma unroll
    for (int cf=0; cf<2; ++cf){
      float bv[8];
#pragma unroll
      for (int j=0;j<8;++j) bv[j] = bp[(size_t)j*HH + cf*16];
      short8 bh, bl;
      split8(bv, &bh, &bl);
      acc[cf] = __builtin_amdgcn_mfma_f32_16x16x32_bf16(ah, bh, acc[cf], 0, 0, 0);
      acc[cf] = __builtin_amdgcn_mfma_f32_16x16x32_bf16(ah, bl, acc[cf], 0, 0, 0);
      acc[cf] = __builtin_amdgcn_mfma_f32_16x16x32_bf16(al, bh, acc[cf], 0, 0, 0);
    }
  }
  const float rs = 0.99999500003750f;
#pragma unroll
  for (int cf=0; cf<2; ++cf){
    int c = c0 + cf*16 + m;
    float sc = 0.f, bi = 0.f, be = 0.f;
    if (!pre){ sc = gam[c]*rs; bi = bias[c]; be = bet[c]; }
#pragma unroll
    for (int i=0;i<4;++i){
      int r = ry*64 + w*16 + q*4 + i;
      float vv = acc[cf][i];
      if (pre) vv += pre[(size_t)r*HH + c];
      else vv = gelu_f((vv + bi)*sc + be);
      out[(size_t)r*HH + c] = vv;
    }
  }
}

// ========== cooperative back-end: G1 -> G2 -> G3 -> final, one dispatch ==========
__global__ __launch_bounds__(256) void kback(
    const float* __restrict__ S, const float* __restrict__ w2n, const float* __restrict__ w2e,
    float* __restrict__ gh,
    const float* __restrict__ ow1, const float* __restrict__ ob1,
    const float* __restrict__ og1, const float* __restrict__ obe1, float* __restrict__ xg2,
    const float* __restrict__ ow2, const float* __restrict__ ob2,
    const float* __restrict__ og2, const float* __restrict__ obe2, float* __restrict__ x2f,
    const float* __restrict__ ow3, const float* __restrict__ ob3, float* __restrict__ out){
  cooperative_groups::grid_group grid = cooperative_groups::this_grid();
  const int cx = blockIdx.x & 15, ry = blockIdx.x >> 4;
  gemm_nolds(cx, ry, S, 1024, 32, w2n, w2e, gh, gh, nullptr, nullptr, nullptr);
  grid.sync();
  gemm_nolds(cx, ry, gh, 512, 16, ow1, ow1, xg2, nullptr, ob1, og1, obe1);
  grid.sync();
  gemm_nolds(cx, ry, xg2, 512, 16, ow2, ow2, x2f, nullptr, ob2, og2, obe2);
  grid.sync();
  // final: out = x2f @ ow3 + ob3   (4 rows/block, 1 row/wave)
  const int lane = threadIdx.x & 63, wv = threadIdx.x >> 6;
  const int r = blockIdx.x*4 + wv;
  float a0 = 0.f, a1 = 0.f;
#pragma unroll
  for (int tt=0; tt<8; ++tt){
    int k = lane + tt*64;
    float x = x2f[(size_t)r*HH + k];
    a0 = __builtin_fmaf(x, ow3[2*k], a0);
    a1 = __builtin_fmaf(x, ow3[2*k+1], a1);
  }
#pragma unroll
  for (int d=1; d<64; d<<=1){ a0 += __shfl_xor(a0, d); a1 += __shfl_xor(a1, d); }
  if (lane == 0){ out[r*2] = a0 + ob3[0]; out[r*2+1] = a1 + ob3[1]; }
}

extern "C" void kernel_launch(void* const* d_in, const int* in_sizes, int n_in,
                              void* d_out, int out_size, void* d_ws, size_t ws_size,
                              hipStream_t stream) {
  const float* nf    = (const float*)d_in[0];
  const float* ef    = (const float*)d_in[1];
  const float* gf    = (const float*)d_in[2];
  const float* dp    = (const float*)d_in[3];
  const int*   ny    = (const int*)d_in[4];
  const int*   bidx  = (const int*)d_in[5];
  const int*   eidx  = (const int*)d_in[6];
  const float* nfw1  = (const float*)d_in[7];
  const float* nfb1  = (const float*)d_in[8];
  const float* nfg1  = (const float*)d_in[9];
  const float* nfbe1 = (const float*)d_in[10];
  const float* w2n   = (const float*)d_in[11];
  const float* b2n   = (const float*)d_in[12];
  const float* efw1  = (const float*)d_in[13];
  const float* efb1  = (const float*)d_in[14];
  const float* efg1  = (const float*)d_in[15];
  const float* efbe1 = (const float*)d_in[16];
  const float* w2e   = (const float*)d_in[17];
  const float* b2e   = (const float*)d_in[18];
  const float* ow1   = (const float*)d_in[19];
  const float* ob1   = (const float*)d_in[20];
  const float* og1   = (const float*)d_in[21];
  const float* obe1  = (const float*)d_in[22];
  const float* ow2   = (const float*)d_in[23];
  const float* ob2   = (const float*)d_in[24];
  const float* og2   = (const float*)d_in[25];
  const float* obe2  = (const float*)d_in[26];
  const float* ow3   = (const float*)d_in[27];
  const float* ob3   = (const float*)d_in[28];

  float* S    = (float*)d_ws;                 // 1024 x 1024
  int* cursor = (int*)(S + NG*1024);          // 1024
  int* nstart = cursor + NG;                  // 1025
  int* estart = nstart + NG + 1;              // 1025
  int* eg     = estart + NG + 1;              // NE
  int* perm   = eg + NE;                      // NE
  int* hpart  = perm + NE;                    // 256*1024
  unsigned short* w1nT = (unsigned short*)(hpart + 256*NG);  // 512*64
  unsigned short* w1eT = w1nT + HH*64;                       // 512*32
  float* b1n  = (float*)(w1eT + HH*32);       // 512
  float* b1e  = b1n + HH;                     // 512
  float* gh   = b1e + HH;                     // 1024*512
  float* xg2  = gh + NG*HH;                   // 1024*512
  float* x2f  = xg2 + NG*HH;                  // 1024*512
  float* outf = (float*)d_out;

  kpre<<<1234, 256, 0, stream>>>(nfw1, nfb1, nfg1, nfbe1, efw1, efb1, efg1, efbe1,
                                 w1nT, w1eT, b1n, b1e, bidx, nstart, eidx, eg, hpart);
  kscan<<<1, 1024, 0, stream>>>(hpart, cursor, estart);
  kscatter<<<128, 1024, 0, stream>>>(eg, cursor, perm, estart, nstart, gf, b2n, b2e, gh);
  kmain<<<6144, 256, 0, stream>>>(nf, dp, ny, nstart, ef, perm, estart,
                                  w1nT, w1eT, b1n, b1e, S);
  void* bargs[] = { (void*)&S, (void*)&w2n, (void*)&w2e, (void*)&gh,
                    (void*)&ow1, (void*)&ob1, (void*)&og1, (void*)&obe1, (void*)&xg2,
                    (void*)&ow2, (void*)&ob2, (void*)&og2, (void*)&obe2, (void*)&x2f,
                    (void*)&ow3, (void*)&ob3, (void*)&outf };
  hipLaunchCooperativeKernel((void*)kback, dim3(256), dim3(256), bargs, 0, stream);
}

// Round 13
// 372.006 us; speedup vs baseline: 1.3773x; 1.3773x over previous
//
#include <hip/hip_runtime.h>
#include <hip/hip_bf16.h>

#define NN 200000
#define NE 600000
#define NG 1024
#define HH 512

typedef short short8 __attribute__((ext_vector_type(8)));
typedef float f32x4 __attribute__((ext_vector_type(4)));

__device__ __forceinline__ unsigned short f2bf(float f){
  unsigned u = __float_as_uint(f);
  u += 0x7fffu + ((u >> 16) & 1u);
  return (unsigned short)(u >> 16);
}
__device__ __forceinline__ float bf2f(unsigned short h){
  return __uint_as_float(((unsigned)h) << 16);
}

// packed f32x8 -> bf16x8 (RTNE)
__device__ __forceinline__ short8 cvt8pk(float4 a, float4 b){
  union { short8 s; __hip_bfloat162 h[4]; } u;
  u.h[0] = __float22bfloat162_rn(make_float2(a.x, a.y));
  u.h[1] = __float22bfloat162_rn(make_float2(a.z, a.w));
  u.h[2] = __float22bfloat162_rn(make_float2(b.x, b.y));
  u.h[3] = __float22bfloat162_rn(make_float2(b.z, b.w));
  return u.s;
}

// f32x8 -> bf16 hi + bf16 lo (split-precision)
__device__ __forceinline__ void split8(const float* v, short8* hi, short8* lo){
  union { short8 s; __hip_bfloat162 h[4]; unsigned u[4]; } H, L;
#pragma unroll
  for (int p=0;p<4;++p){
    float a = v[2*p], b = v[2*p+1];
    H.h[p] = __float22bfloat162_rn(make_float2(a, b));
    unsigned hu = H.u[p];
    L.h[p] = __float22bfloat162_rn(make_float2(a - __uint_as_float(hu << 16),
                                               b - __uint_as_float(hu & 0xffff0000u)));
  }
  *hi = H.s; *lo = L.s;
}

// gelu(x) = x * sigmoid(1.5957691216*x + 0.07135481627*x^3)  (tanh-form GELU)
__device__ __forceinline__ float gelu_f(float x){
  float p = __builtin_fmaf(x*x, -0.10294325f, -2.3022085f);
  float e = __builtin_amdgcn_exp2f(x * p);
  return x * __builtin_amdgcn_rcpf(1.0f + e);
}

// ========== kpre: w1 prep(196) + nstart(782) + edge histogram over CONTIGUOUS ranges(256) ==========
__global__ __launch_bounds__(256) void kpre(
    const float* __restrict__ nfw1, const float* __restrict__ nfb1,
    const float* __restrict__ nfg1, const float* __restrict__ nfbe1,
    const float* __restrict__ efw1, const float* __restrict__ efb1,
    const float* __restrict__ efg1, const float* __restrict__ efbe1,
    unsigned short* __restrict__ w1nT, unsigned short* __restrict__ w1eT,
    float* __restrict__ b1n, float* __restrict__ b1e,
    const int* __restrict__ bidx, int* __restrict__ nstart,
    const int* __restrict__ eidx, int* __restrict__ eg, int* __restrict__ hpart){
  __shared__ int h[NG];
  const float rs = 0.99999500003750f;   // 1/sqrt(1+1e-5)
  int b = blockIdx.x, t = threadIdx.x;
  if (b < 196){
    int tid = b*256 + t;
    if (tid < 512*64){
      int c = tid >> 6, k = tid & 63;
      float w = (k < 41) ? nfw1[k*HH + c] * nfg1[c] * rs : 0.0f;
      w1nT[tid] = f2bf(w);
    } else if (tid < 512*96){
      int u = tid - 512*64; int c = u >> 5, k = u & 31;
      float w = (k < 16) ? efw1[k*HH + c] * efg1[c] * rs : 0.0f;
      w1eT[u] = f2bf(w);
    } else if (tid < 512*96 + 512){
      int c = tid - 512*96;
      b1n[c] = nfb1[c]*nfg1[c]*rs + nfbe1[c];
    } else if (tid < 512*96 + 1024){
      int c = tid - (512*96 + 512);
      b1e[c] = efb1[c]*efg1[c]*rs + efbe1[c];
    }
  } else if (b < 978){
    int i = (b-196)*256 + t;
    if (i < NN){
      int g0 = bidx[i];
      int g1 = (i+1 < NN) ? bidx[i+1] : NG;
      for (int g = g0+1; g <= g1; ++g) nstart[g] = i+1;
      if (i == 0) for (int g = 0; g <= g0; ++g) nstart[g] = 0;
    }
  } else {
    int hb = b - 978;                     // 0..255, contiguous edge range
    for (int u = t; u < NG; u += 256) h[u] = 0;
    __syncthreads();
    const int per = (NE + 255) / 256;
    const int lo = hb*per, hi = min(lo + per, NE);
    for (int e = lo + t; e < hi; e += 256){
      int g = bidx[eidx[e]];
      eg[e] = g;
      atomicAdd(&h[g], 1);
    }
    __syncthreads();
    for (int u = t; u < NG; u += 256) hpart[hb*NG + u] = h[u];
  }
}

// ========== kscat: per-block inline scan of hpart -> atomic-free scatter + estart + gh-init ==========
__global__ __launch_bounds__(1024) void kscat(const int* __restrict__ eg,
    const int* __restrict__ hpart, int* __restrict__ estart, int* __restrict__ perm,
    const int* __restrict__ nstart, const float* __restrict__ gf,
    const float* __restrict__ b2n, const float* __restrict__ b2e, float* __restrict__ gh){
  __shared__ int s[NG];
  __shared__ int h[NG];
  __shared__ int base[NG];
  const int b = blockIdx.x, t = threadIdx.x;
  int T = 0, P = 0;
  for (int hb = 0; hb < 256; ++hb){
    int hp = hpart[hb*NG + t];
    T += hp;
    if (hb < b) P += hp;
  }
  s[t] = T; __syncthreads();
  for (int d = 1; d < NG; d <<= 1){
    int x = (t >= d) ? s[t-d] : 0;
    __syncthreads();
    s[t] += x;
    __syncthreads();
  }
  const int excl = s[t] - T;
  base[t] = excl + P;
  h[t] = 0;
  if (b == 0){
    estart[t] = excl;
    if (t == NG-1) estart[NG] = s[t];   // == NE
  }
  __syncthreads();
  const int per = (NE + 255) / 256;
  const int lo = b*per, hi = min(lo + per, NE);
  for (int e = lo + t; e < hi; e += 1024){
    int g = eg[e];
    int p = base[g] + atomicAdd(&h[g], 1);
    perm[p] = e;
  }
  // gh-init: gh = gf + cntn*b2n + cnte*b2e   (512 float4 per block; cnte from LDS scan)
  if (t < 512){
    int i = b*512 + t;                  // 131072 = NG*HH/4 total
    int f = i*4;
    int r = f >> 9, c = f & 511;
    float cn = (float)(nstart[r+1] - nstart[r]);
    float ce = (float)(s[r] - ((r > 0) ? s[r-1] : 0));
    float4 gv = *(const float4*)&gf[f];
    float4 bn4 = *(const float4*)&b2n[c];
    float4 be4 = *(const float4*)&b2e[c];
    float4 o;
    o.x = gv.x + cn*bn4.x + ce*be4.x;
    o.y = gv.y + cn*bn4.y + ce*be4.y;
    o.z = gv.z + cn*bn4.z + ce*be4.z;
    o.w = gv.w + cn*bn4.w + ce*be4.w;
    *(float4*)&gh[f] = o;
  }
}

// ========== fused first layers (round-6 structure + pk-convert staging; measured 170us) ==========
__global__ __launch_bounds__(256) void kmain(
    const float* __restrict__ nf, const float* __restrict__ dp, const int* __restrict__ ny,
    const int* __restrict__ nstart, const float* __restrict__ ef, const int* __restrict__ perm,
    const int* __restrict__ estart, const unsigned short* __restrict__ w1nT,
    const unsigned short* __restrict__ w1eT, const float* __restrict__ b1n,
    const float* __restrict__ b1e, float* __restrict__ S){
  const int t = threadIdx.x;
  const int lane = t & 63, w = t >> 6;
  const int q = lane >> 4, m = lane & 15;
  const short8 zz = {0,0,0,0,0,0,0,0};
  if (blockIdx.x < 2048){
    // ---------------- EDGE ----------------
    const int g = blockIdx.x >> 1;
    const int c0 = ((blockIdx.x & 1) << 8) + (w << 6);
    short8 bfr[4]; float bias[4]; float colacc[4] = {0.f,0.f,0.f,0.f};
#pragma unroll
    for (int nt=0; nt<4; ++nt){
      int c = c0 + (nt<<4) + m;
      bfr[nt] = *(const short8*)(w1eT + (c << 5) + (q << 3));
      bias[nt] = b1e[c];
    }
    const int s0 = estart[g], s1 = estart[g+1];
    const int nfull = (s1 - s0) >> 4;
    int rb = s0;
    for (int ch=0; ch<nfull; ++ch, rb += 16){
      int e = perm[rb + m];
      short8 f = zz;
      if (q < 2){
        const float4* ap = (const float4*)(ef + (size_t)e*16 + (q<<3));
        f = cvt8pk(ap[0], ap[1]);
      }
#pragma unroll
      for (int nt=0; nt<4; ++nt){
        f32x4 acc = {bias[nt], bias[nt], bias[nt], bias[nt]};
        acc = __builtin_amdgcn_mfma_f32_16x16x32_bf16(f, bfr[nt], acc, 0, 0, 0);
        colacc[nt] += (gelu_f(acc[0]) + gelu_f(acc[1])) + (gelu_f(acc[2]) + gelu_f(acc[3]));
      }
    }
    if (rb < s1){
      int row = rb + m;
      int e = perm[(row < s1) ? row : s0];
      short8 f = zz;
      if (q < 2){
        const float4* ap = (const float4*)(ef + (size_t)e*16 + (q<<3));
        f = cvt8pk(ap[0], ap[1]);
      }
      const int vr = s1 - rb;   // 1..15 valid rows in this chunk
#pragma unroll
      for (int nt=0; nt<4; ++nt){
        f32x4 acc = {bias[nt], bias[nt], bias[nt], bias[nt]};
        acc = __builtin_amdgcn_mfma_f32_16x16x32_bf16(f, bfr[nt], acc, 0, 0, 0);
        float v0 = (q*4+0 < vr) ? gelu_f(acc[0]) : 0.f;
        float v1 = (q*4+1 < vr) ? gelu_f(acc[1]) : 0.f;
        float v2 = (q*4+2 < vr) ? gelu_f(acc[2]) : 0.f;
        float v3 = (q*4+3 < vr) ? gelu_f(acc[3]) : 0.f;
        colacc[nt] += (v0+v1)+(v2+v3);
      }
    }
#pragma unroll
    for (int nt=0; nt<4; ++nt){
      float s = colacc[nt];
      s += __shfl_xor(s, 16); s += __shfl_xor(s, 32);
      if (lane < 16) S[(size_t)g*1024 + 512 + c0 + (nt<<4) + lane] = s;
    }
  } else {
    // ---------------- NODE ----------------
    const int b2 = blockIdx.x - 2048;
    const int g = b2 >> 2;
    const int c0 = ((b2 & 3) << 7) + (w << 5);
    short8 bf0[2], bf1[2]; float bias[2]; float colacc[2] = {0.f,0.f};
#pragma unroll
    for (int nt=0; nt<2; ++nt){
      int c = c0 + (nt<<4) + m;
      const short8* bp = (const short8*)(w1nT + (c << 6) + (q << 3));
      bf0[nt] = bp[0]; bf1[nt] = bp[4];
      bias[nt] = b1n[c];
    }
    const int s0 = nstart[g], s1 = nstart[g+1];
    const int nfull = (s1 - s0) >> 4;
    int rb = s0;
    for (int ch=0; ch<nfull; ++ch, rb += 16){
      int ar = rb + m;
      const float4* ap = (const float4*)(nf + (size_t)ar*32 + (q<<3));
      short8 f = cvt8pk(ap[0], ap[1]);
      int cls = ny[ar];
      short dpb = (short)f2bf(dp[ar]);
      short8 h = zz;
      if (q == 0){
#pragma unroll
        for (int j=0;j<8;++j) h[j] = (cls==j) ? dpb : (short)0;
      } else if (q == 1 && cls == 8) h[0] = dpb;
#pragma unroll
      for (int nt=0; nt<2; ++nt){
        f32x4 acc = {bias[nt], bias[nt], bias[nt], bias[nt]};
        acc = __builtin_amdgcn_mfma_f32_16x16x32_bf16(f, bf0[nt], acc, 0, 0, 0);
        acc = __builtin_amdgcn_mfma_f32_16x16x32_bf16(h, bf1[nt], acc, 0, 0, 0);
        colacc[nt] += (gelu_f(acc[0]) + gelu_f(acc[1])) + (gelu_f(acc[2]) + gelu_f(acc[3]));
      }
    }
    if (rb < s1){
      int row = rb + m;
      int ar = (row < s1) ? row : s0;
      const float4* ap = (const float4*)(nf + (size_t)ar*32 + (q<<3));
      short8 f = cvt8pk(ap[0], ap[1]);
      int cls = ny[ar];
      short dpb = (short)f2bf(dp[ar]);
      short8 h = zz;
      if (q == 0){
#pragma unroll
        for (int j=0;j<8;++j) h[j] = (cls==j) ? dpb : (short)0;
      } else if (q == 1 && cls == 8) h[0] = dpb;
      const int vr = s1 - rb;
#pragma unroll
      for (int nt=0; nt<2; ++nt){
        f32x4 acc = {bias[nt], bias[nt], bias[nt], bias[nt]};
        acc = __builtin_amdgcn_mfma_f32_16x16x32_bf16(f, bf0[nt], acc, 0, 0, 0);
        acc = __builtin_amdgcn_mfma_f32_16x16x32_bf16(h, bf1[nt], acc, 0, 0, 0);
        float v0 = (q*4+0 < vr) ? gelu_f(acc[0]) : 0.f;
        float v1 = (q*4+1 < vr) ? gelu_f(acc[1]) : 0.f;
        float v2 = (q*4+2 < vr) ? gelu_f(acc[2]) : 0.f;
        float v3 = (q*4+3 < vr) ? gelu_f(acc[3]) : 0.f;
        colacc[nt] += (v0+v1)+(v2+v3);
      }
    }
#pragma unroll
    for (int nt=0; nt<2; ++nt){
      float s = colacc[nt];
      s += __shfl_xor(s, 16); s += __shfl_xor(s, 32);
      if (lane < 16) S[(size_t)g*1024 + c0 + (nt<<4) + lane] = s;
    }
  }
}

// ========== LDS-free bf16 split (hi+lo) MFMA GEMM, B direct from fp32 weights ==========
__global__ __launch_bounds__(256) void kgemm3(const float* __restrict__ A, int lda, int nkc,
    const float* __restrict__ B0, const float* __restrict__ B1,
    float* __restrict__ out, const float* __restrict__ pre, const float* __restrict__ bias,
    const float* __restrict__ gam, const float* __restrict__ bet){
  const int t = threadIdx.x, lane = t & 63, w = t >> 6;
  const int q = lane >> 4, m = lane & 15;
  const int c0 = blockIdx.x*32, r0 = blockIdx.y*64 + w*16;
  f32x4 acc[2] = {{0.f,0.f,0.f,0.f},{0.f,0.f,0.f,0.f}};
  const float* ap = A + (size_t)(r0 + m)*lda + (q<<3);
  for (int kc = 0; kc < nkc; ++kc){
    const int ko = kc*32;
    float4 x = *(const float4*)(ap + ko);
    float4 y = *(const float4*)(ap + ko + 4);
    float v[8] = {x.x,x.y,x.z,x.w,y.x,y.y,y.z,y.w};
    short8 ah, al;
    split8(v, &ah, &al);
    const float* Bp = (kc < 16) ? B0 : B1;
    const float* bp = Bp + (size_t)((kc & 15)*32 + (q<<3))*HH + c0 + m;
#pragma unroll
    for (int cf=0; cf<2; ++cf){
      float bv[8];
#pragma unroll
      for (int j=0;j<8;++j) bv[j] = bp[(size_t)j*HH + cf*16];
      short8 bh, bl;
      split8(bv, &bh, &bl);
      acc[cf] = __builtin_amdgcn_mfma_f32_16x16x32_bf16(ah, bh, acc[cf], 0, 0, 0);
      acc[cf] = __builtin_amdgcn_mfma_f32_16x16x32_bf16(ah, bl, acc[cf], 0, 0, 0);
      acc[cf] = __builtin_amdgcn_mfma_f32_16x16x32_bf16(al, bh, acc[cf], 0, 0, 0);
    }
  }
  const float rs = 0.99999500003750f;
#pragma unroll
  for (int cf=0; cf<2; ++cf){
    int c = c0 + cf*16 + m;
    float sc = 0.f, bi = 0.f, be = 0.f;
    if (!pre){ sc = gam[c]*rs; bi = bias[c]; be = bet[c]; }
#pragma unroll
    for (int i=0;i<4;++i){
      int r = blockIdx.y*64 + w*16 + q*4 + i;
      float vv = acc[cf][i];
      if (pre) vv += pre[(size_t)r*HH + c];
      else vv = gelu_f((vv + bi)*sc + be);
      out[(size_t)r*HH + c] = vv;
    }
  }
}

// ========== final 512 -> 2 linear ==========
__global__ __launch_bounds__(256) void kfinal(const float* __restrict__ x2, const float* __restrict__ w3,
    const float* __restrict__ b3, float* __restrict__ out){
  const int lane = threadIdx.x & 63, wv = threadIdx.x >> 6;
  const int r = blockIdx.x*4 + wv;
  float a0 = 0.f, a1 = 0.f;
#pragma unroll
  for (int tt=0; tt<8; ++tt){
    int k = lane + tt*64;
    float x = x2[(size_t)r*HH + k];
    a0 = __builtin_fmaf(x, w3[2*k], a0);
    a1 = __builtin_fmaf(x, w3[2*k+1], a1);
  }
#pragma unroll
  for (int d=1; d<64; d<<=1){ a0 += __shfl_xor(a0, d); a1 += __shfl_xor(a1, d); }
  if (lane == 0){ out[r*2] = a0 + b3[0]; out[r*2+1] = a1 + b3[1]; }
}

extern "C" void kernel_launch(void* const* d_in, const int* in_sizes, int n_in,
                              void* d_out, int out_size, void* d_ws, size_t ws_size,
                              hipStream_t stream) {
  const float* nf    = (const float*)d_in[0];
  const float* ef    = (const float*)d_in[1];
  const float* gf    = (const float*)d_in[2];
  const float* dp    = (const float*)d_in[3];
  const int*   ny    = (const int*)d_in[4];
  const int*   bidx  = (const int*)d_in[5];
  const int*   eidx  = (const int*)d_in[6];
  const float* nfw1  = (const float*)d_in[7];
  const float* nfb1  = (const float*)d_in[8];
  const float* nfg1  = (const float*)d_in[9];
  const float* nfbe1 = (const float*)d_in[10];
  const float* w2n   = (const float*)d_in[11];
  const float* b2n   = (const float*)d_in[12];
  const float* efw1  = (const float*)d_in[13];
  const float* efb1  = (const float*)d_in[14];
  const float* efg1  = (const float*)d_in[15];
  const float* efbe1 = (const float*)d_in[16];
  const float* w2e   = (const float*)d_in[17];
  const float* b2e   = (const float*)d_in[18];
  const float* ow1   = (const float*)d_in[19];
  const float* ob1   = (const float*)d_in[20];
  const float* og1   = (const float*)d_in[21];
  const float* obe1  = (const float*)d_in[22];
  const float* ow2   = (const float*)d_in[23];
  const float* ob2   = (const float*)d_in[24];
  const float* og2   = (const float*)d_in[25];
  const float* obe2  = (const float*)d_in[26];
  const float* ow3   = (const float*)d_in[27];
  const float* ob3   = (const float*)d_in[28];

  float* S    = (float*)d_ws;                 // 1024 x 1024
  int* nstart = (int*)(S + NG*1024);          // 1025
  int* estart = nstart + NG + 1;              // 1025
  int* eg     = estart + NG + 1;              // NE
  int* perm   = eg + NE;                      // NE
  int* hpart  = perm + NE;                    // 256*1024
  unsigned short* w1nT = (unsigned short*)(hpart + 256*NG);  // 512*64
  unsigned short* w1eT = w1nT + HH*64;                       // 512*32
  float* b1n  = (float*)(w1eT + HH*32);       // 512
  float* b1e  = b1n + HH;                     // 512
  float* gh   = b1e + HH;                     // 1024*512
  float* xg2  = gh + NG*HH;                   // 1024*512
  float* x2f  = xg2 + NG*HH;                  // 1024*512

  kpre<<<1234, 256, 0, stream>>>(nfw1, nfb1, nfg1, nfbe1, efw1, efb1, efg1, efbe1,
                                 w1nT, w1eT, b1n, b1e, bidx, nstart, eidx, eg, hpart);
  kscat<<<256, 1024, 0, stream>>>(eg, hpart, estart, perm, nstart, gf, b2n, b2e, gh);
  kmain<<<6144, 256, 0, stream>>>(nf, dp, ny, nstart, ef, perm, estart,
                                  w1nT, w1eT, b1n, b1e, S);
  // G1: gh = S @ [w2n;w2e] + gh_pre   (K=1024, in-place pre)
  kgemm3<<<dim3(16,16), 256, 0, stream>>>(S, 1024, 32, w2n, w2e, gh, gh,
                                          nullptr, nullptr, nullptr);
  // G2: xg2 = gelu(bn(gh @ ow1 + ob1))
  kgemm3<<<dim3(16,16), 256, 0, stream>>>(gh, 512, 16, ow1, ow1, xg2, nullptr,
                                          ob1, og1, obe1);
  // G3: x2f = gelu(bn(xg2 @ ow2 + ob2))
  kgemm3<<<dim3(16,16), 256, 0, stream>>>(xg2, 512, 16, ow2, ow2, x2f, nullptr,
                                          ob2, og2, obe2);
  kfinal<<<NG/4, 256, 0, stream>>>(x2f, ow3, ob3, (float*)d_out);
}